// Round 1
// baseline (109.658 us; speedup 1.0000x reference)
//
#include <hip/hip_runtime.h>

#define NTOK 16384   // B*T = 4*4096
#define BQ 4
#define TQ 4096
#define SQ 8192
#define BLK 1024
#define PER_T (NTOK / BLK)   // 16 elements per thread
#define NWAVE (BLK / 64)     // 16 waves

// Kernel A: exact stable top-K selection via 4-level radix refinement.
__global__ __launch_bounds__(BLK) void select_tokens_kernel(
    const float* __restrict__ scores,
    const int* __restrict__ cand,
    const int* __restrict__ tok,
    const int* __restrict__ kptr,
    int* __restrict__ out0)
{
    __shared__ unsigned keys[NTOK];        // 64 KB
    __shared__ int histw[NWAVE][256];      // 16 KB per-wave histograms
    __shared__ int sufs[256];
    __shared__ int scanbuf[BLK];
    __shared__ unsigned s_prefix, s_mask;
    __shared__ int s_krem;

    const int tid = threadIdx.x;
    const int K = kptr[0];

    // Load scores (coalesced), convert to order-preserving unsigned keys.
    for (int t = 0; t < PER_T; ++t) {
        int i = t * BLK + tid;
        unsigned u = __float_as_uint(scores[i]);
        if ((u << 1) == 0u) u = 0u;  // normalize -0.0 -> +0.0 (float == semantics)
        keys[i] = (u & 0x80000000u) ? ~u : (u | 0x80000000u);
    }
    if (tid == 0) { s_prefix = 0u; s_mask = 0u; s_krem = K; }
    __syncthreads();

    const bool none = (K <= 0);
    const bool all  = (K >= NTOK);

    if (!none && !all) {
        for (int level = 0; level < 4; ++level) {
            const int shift = 24 - 8 * level;
            // zero per-wave histograms
            for (int t = tid; t < NWAVE * 256; t += BLK) ((int*)histw)[t] = 0;
            __syncthreads();
            const unsigned pf = s_prefix, mk = s_mask;
            const int krem = s_krem;
            const int wid = tid >> 6;
            for (int t = 0; t < PER_T; ++t) {
                unsigned key = keys[tid * PER_T + t];
                if ((key & mk) == pf)
                    atomicAdd(&histw[wid][(key >> shift) & 0xFF], 1);
            }
            __syncthreads();
            if (tid < 256) {
                int s = 0;
                #pragma unroll
                for (int w = 0; w < NWAVE; ++w) s += histw[w][tid];
                sufs[tid] = s;
            }
            __syncthreads();
            // suffix sum: sufs[b] = count of keys in group with byte >= b
            for (int off = 1; off < 256; off <<= 1) {
                int v = 0;
                if (tid < 256) { v = sufs[tid]; if (tid + off < 256) v += sufs[tid + off]; }
                __syncthreads();
                if (tid < 256) sufs[tid] = v;
                __syncthreads();
            }
            // unique boundary bin b: sufs[b] >= krem > sufs[b+1]
            if (tid < 256) {
                int above = (tid < 255) ? sufs[tid + 1] : 0;
                if (sufs[tid] >= krem && above < krem) {
                    s_prefix = pf | ((unsigned)tid << shift);
                    s_mask   = mk | (0xFFu << shift);
                    s_krem   = krem - above;
                }
            }
            __syncthreads();
        }
    }

    const unsigned Tstar = s_prefix;
    const int R = s_krem;  // number of ==Tstar elements to select, in index order

    // stable tie-break: exclusive prefix (by index) of equal-key counts
    int cnt = 0;
    if (!none && !all) {
        for (int t = 0; t < PER_T; ++t) cnt += (keys[tid * PER_T + t] == Tstar) ? 1 : 0;
    }
    scanbuf[tid] = cnt;
    __syncthreads();
    for (int off = 1; off < BLK; off <<= 1) {
        int v = scanbuf[tid];
        int add = (tid >= off) ? scanbuf[tid - off] : 0;
        __syncthreads();
        scanbuf[tid] = v + add;
        __syncthreads();
    }
    int running = scanbuf[tid] - cnt;  // exclusive prefix of equals before my chunk

    for (int t = 0; t < PER_T; ++t) {
        int i = tid * PER_T + t;
        unsigned key = keys[i];
        bool sel;
        if (none)             sel = false;
        else if (all)         sel = true;
        else if (key > Tstar) sel = true;
        else if (key == Tstar) { sel = (running < R); ++running; }
        else                  sel = false;
        out0[i] = sel ? cand[i] : tok[i];
    }
}

// Kernel B: build upd = batch_input_ids with windows overwritten by updated tokens.
__global__ __launch_bounds__(256) void write_upd_kernel(
    const int* __restrict__ in_bids,
    const int* __restrict__ upd_tok,
    int* __restrict__ out1)
{
    int idx = blockIdx.x * 256 + threadIdx.x;   // < 2*BQ*SQ = 65536
    int c   = idx >> 15;          // / (BQ*SQ) = 32768
    int rem = idx & 32767;
    int b   = rem >> 13;          // / SQ = 8192
    int s   = rem & 8191;
    int v;
    if (c == 0) {
        // plane 0: cols [S-T, S) <- updated tokens
        v = (s >= (SQ - TQ)) ? upd_tok[(b << 12) + (s - (SQ - TQ))] : in_bids[idx];
    } else {
        // plane 1: cols [0, T) <- updated tokens
        v = (s < TQ) ? upd_tok[(b << 12) + s] : in_bids[idx];
    }
    out1[idx] = v;
}

extern "C" void kernel_launch(void* const* d_in, const int* in_sizes, int n_in,
                              void* d_out, int out_size, void* d_ws, size_t ws_size,
                              hipStream_t stream) {
    const int*   tok    = (const int*)d_in[0];   // tokens          [4,4096]
    const int*   bids   = (const int*)d_in[1];   // batch_input_ids [2,4,8192]
    const int*   cand   = (const int*)d_in[2];   // candidate_tokens[4,4096]
    const float* scores = (const float*)d_in[3]; // candidate_scores[4,4096]
    const int*   kptr   = (const int*)d_in[4];   // unmask_count scalar

    int* out0 = (int*)d_out;        // updated_tokens, 16384 ints
    int* out1 = out0 + NTOK;        // upd, 65536 ints

    select_tokens_kernel<<<1, BLK, 0, stream>>>(scores, cand, tok, kptr, out0);
    write_upd_kernel<<<(2 * BQ * SQ) / 256, 256, 0, stream>>>(bids, out0, out1);
}

// Round 2
// 70.503 us; speedup vs baseline: 1.5554x; 1.5554x over previous
//
#include <hip/hip_runtime.h>

#define NTOK 16384   // B*T = 4*4096
#define BQ 4
#define TQ 4096
#define SQ 8192
#define BLK 1024
#define PER_T 16
#define NSLOT 32
#define HPAD 33      // hist[bin][slot] padded: bank = (bin+slot)%32 -> conflict-free

__device__ __forceinline__ unsigned score_key(float s) {
    unsigned u = __float_as_uint(s);
    if ((u << 1) == 0u) u = 0u;                 // -0.0 == +0.0
    return (u & 0x80000000u) ? ~u : (u | 0x80000000u);
}

__global__ __launch_bounds__(BLK) void token_update_kernel(
    const float* __restrict__ scores,
    const int* __restrict__ cand,
    const int* __restrict__ tok,
    const int* __restrict__ bids,
    const int* __restrict__ kptr,
    int* __restrict__ out0,
    int* __restrict__ out1)
{
    const int tid = threadIdx.x;

    if (blockIdx.x > 0) {
        // Blocks 1..8: copy the non-window halves of bids -> out1 (int4).
        // plane0 non-window: s in [0, S-T); plane1 non-window: s in [T, S).
        int g  = (blockIdx.x - 1) * BLK + tid;      // [0, 8192)
        int o4 = g << 2;                            // int offset in [0, 32768)
        int c  = o4 >> 12;                          // chunk 0..7 (4096 ints each)
        int b  = c & 3, plane = c >> 2;
        int off = o4 & 4095;
        int addr = (plane == 0) ? (b * SQ + off)
                                : (BQ * SQ + b * SQ + TQ + off);
        *(int4*)(out1 + addr) = *(const int4*)(bids + addr);
        return;
    }

    // ---- Block 0: exact stable top-K selection (4-level radix refine) ----
    __shared__ int hist[256][HPAD];   // ~33 KB
    __shared__ int cnt[256];
    __shared__ int scanbuf[BLK];      // rare-path tie-break only
    __shared__ unsigned s_prefix;
    __shared__ int s_krem, s_E;

    const int K = kptr[0];
    const bool none = (K <= 0);
    const bool all  = (K >= NTOK);
    const bool run  = !none && !all;
    const int slot = tid & (NSLOT - 1);

    for (int t = tid; t < 256 * HPAD; t += BLK) ((int*)hist)[t] = 0;
    if (tid == 0) { s_prefix = 0u; s_krem = K; s_E = K; }
    __syncthreads();

    // Load keys into registers (strided/coalesced) + level-0 histogram.
    float sv[PER_T];
    #pragma unroll
    for (int t = 0; t < PER_T; ++t) sv[t] = scores[t * BLK + tid];
    unsigned key[PER_T];
    #pragma unroll
    for (int t = 0; t < PER_T; ++t) {
        unsigned k = score_key(sv[t]);
        key[t] = k;
        atomicAdd(&hist[k >> 24][slot], 1);
    }
    __syncthreads();

    for (int level = 0; level < 4; ++level) {
        // Reduce 32 slots -> cnt[bin]; banks (tid+j)%32: conflict-free.
        if (tid < 256) {
            int s = 0;
            #pragma unroll
            for (int j = 0; j < NSLOT; ++j) s += hist[tid][j];
            cnt[tid] = s;
        }
        __syncthreads();

        // Wave 0: suffix scan over 256 bins + boundary find. No barriers inside.
        if (run && tid < 64) {
            int c0 = cnt[4 * tid], c1 = cnt[4 * tid + 1];
            int c2 = cnt[4 * tid + 2], c3 = cnt[4 * tid + 3];
            int T = c0 + c1 + c2 + c3;
            int incl = T;
            #pragma unroll
            for (int off = 1; off < 64; off <<= 1) {
                int o = __shfl_down(incl, off, 64);
                if (tid + off < 64) incl += o;
            }
            int suf4 = incl - T;          // sum of bins > 4*tid+3
            int suf3 = suf4 + c3;
            int suf2 = suf3 + c2;
            int suf1 = suf2 + c1;
            int suf0 = suf1 + c0;
            int krem = s_krem;
            int shift = 24 - 8 * level;
            int sufs[5] = {suf0, suf1, suf2, suf3, suf4};
            int cs[4] = {c0, c1, c2, c3};
            #pragma unroll
            for (int j = 0; j < 4; ++j) {
                if (sufs[j] >= krem && sufs[j + 1] < krem) {
                    s_prefix = s_prefix | ((unsigned)(4 * tid + j) << shift);
                    s_krem = krem - sufs[j + 1];
                    s_E = cs[j];
                }
            }
        }
        __syncthreads();

        if (level < 3) {
            for (int t = tid; t < 256 * HPAD; t += BLK) ((int*)hist)[t] = 0;
            __syncthreads();
            if (run) {
                unsigned pref = s_prefix;
                int msh = 24 - 8 * level;     // bits fixed so far
                int shift = msh - 8;          // next digit
                #pragma unroll
                for (int t = 0; t < PER_T; ++t) {
                    unsigned k = key[t];
                    if ((k >> msh) == (pref >> msh))
                        atomicAdd(&hist[(k >> shift) & 255][slot], 1);
                }
            }
            __syncthreads();
        }
    }

    const unsigned Tstar = s_prefix;
    const int R = s_krem, E = s_E;

    if (!run || R == E) {
        // Fast path: all keys == Tstar are selected -> sel = (key >= Tstar).
        #pragma unroll
        for (int t = 0; t < PER_T; ++t) {
            int i = t * BLK + tid;
            bool sel = none ? false : (all ? true : (key[t] >= Tstar));
            int v = sel ? cand[i] : tok[i];
            int b = i >> 12, tt = i & 4095;
            out0[i] = v;
            out1[b * SQ + (SQ - TQ) + tt] = v;          // plane 0 window
            out1[BQ * SQ + b * SQ + tt] = v;            // plane 1 window
        }
    } else {
        // Rare path (boundary tie, R < E): stable index-order tie-break.
        // Re-read scores in chunked layout so the prefix is contiguous.
        unsigned ck[PER_T];
        int cntEq = 0;
        #pragma unroll
        for (int j = 0; j < PER_T; ++j) {
            unsigned k = score_key(scores[tid * PER_T + j]);
            ck[j] = k;
            cntEq += (k == Tstar) ? 1 : 0;
        }
        scanbuf[tid] = cntEq;
        __syncthreads();
        for (int off = 1; off < BLK; off <<= 1) {
            int v = scanbuf[tid];
            int add = (tid >= off) ? scanbuf[tid - off] : 0;
            __syncthreads();
            scanbuf[tid] = v + add;
            __syncthreads();
        }
        int running = scanbuf[tid] - cntEq;   // equals before my chunk
        for (int j = 0; j < PER_T; ++j) {
            int i = tid * PER_T + j;
            unsigned k = ck[j];
            bool sel;
            if (k > Tstar) sel = true;
            else if (k == Tstar) { sel = (running < R); ++running; }
            else sel = false;
            int v = sel ? cand[i] : tok[i];
            int b = i >> 12, tt = i & 4095;
            out0[i] = v;
            out1[b * SQ + (SQ - TQ) + tt] = v;
            out1[BQ * SQ + b * SQ + tt] = v;
        }
    }
}

extern "C" void kernel_launch(void* const* d_in, const int* in_sizes, int n_in,
                              void* d_out, int out_size, void* d_ws, size_t ws_size,
                              hipStream_t stream) {
    const int*   tok    = (const int*)d_in[0];   // tokens          [4,4096]
    const int*   bids   = (const int*)d_in[1];   // batch_input_ids [2,4,8192]
    const int*   cand   = (const int*)d_in[2];   // candidate_tokens[4,4096]
    const float* scores = (const float*)d_in[3]; // candidate_scores[4,4096]
    const int*   kptr   = (const int*)d_in[4];   // unmask_count scalar

    int* out0 = (int*)d_out;        // updated_tokens, 16384 ints
    int* out1 = out0 + NTOK;        // upd, 65536 ints

    token_update_kernel<<<9, BLK, 0, stream>>>(scores, cand, tok, bids, kptr, out0, out1);
}